// Round 3
// baseline (332.238 us; speedup 1.0000x reference)
//
#include <hip/hip_runtime.h>
#include <hip/hip_bf16.h>

// y_i = x_i^T Q x_i + b^T x_i + c ; N=16384, D=1024, fp32.
// Round 3: R=32 rows/wave (two 16-row A-groups share each B-frag -> LDS
// B-traffic halves), K-split by 2 (fused dot is linear in k-partials; A-regs
// stay 128/wave), col-split by 4 -> grid 512 = 2 blocks/CU for barrier
// overlap. One barrier per tile; global prefetch issued AFTER the barrier so
// the barrier's vmcnt(0) drain doesn't kill it. atomicAdd partial y.

#define DD 1024
#define KH 512           // K per block (K-split 2)
#define KSTEP 16         // KH/32 MFMA k-steps per tile
#define NT 16            // column tiles per col-segment (64/4)
#define LDS_ROW 520      // 512 + 8 pad shorts (stride 4 mod 32 dwords)

typedef short v8s __attribute__((ext_vector_type(8)));
typedef float v4f __attribute__((ext_vector_type(4)));

__device__ __forceinline__ short f2b(float f) {
    union { __hip_bfloat16 h; short s; } u;
    u.h = __float2bfloat16(f);
    return u.s;
}

__global__ __launch_bounds__(512, 4)
void quad_kernel(const float* __restrict__ x, const float* __restrict__ Q,
                 const float* __restrict__ bvec, const float* __restrict__ cptr,
                 float* __restrict__ y)
{
    __shared__ short lq[2][16 * LDS_ROW];   // 2 x 16.25 KB

    const int tid  = threadIdx.x;
    const int lane = tid & 63;
    const int wave = tid >> 6;
    const int quad = lane >> 4;
    const int l15  = lane & 15;

    // blockIdx = rblk*8 + seg ; seg = colseg*2 + khalf -> blockIdx%8 keys the
    // Q-eighth so same-segment blocks share an XCD's L2 (round-robin heuristic).
    const int seg    = blockIdx.x & 7;
    const int rblk   = blockIdx.x >> 3;      // 0..63
    const int colseg = seg >> 1;             // 0..3
    const int khalf  = seg & 1;              // 0..1

    const int row_base = rblk * 256 + wave * 32;   // 32 rows per wave
    const int kofs  = khalf * KH;
    const int tbase = colseg * NT;

    // ---- Phase 1: A = x[rows 0..31][kofs..kofs+KH) as bf16 frags in AGPRs --
    // A layout (16x16x32): m = lane&15, k = quad*8 + j (8 contiguous bf16)
    v8s a0[KSTEP], a1[KSTEP];
    {
        const float* xr0 = x + (size_t)(row_base + l15) * DD + kofs + quad * 8;
        const float* xr1 = xr0 + (size_t)16 * DD;
        #pragma unroll
        for (int kt = 0; kt < KSTEP; ++kt) {
            float4 f0 = *(const float4*)(xr0 + kt * 32);
            float4 f1 = *(const float4*)(xr0 + kt * 32 + 4);
            v8s a;
            a[0]=f2b(f0.x); a[1]=f2b(f0.y); a[2]=f2b(f0.z); a[3]=f2b(f0.w);
            a[4]=f2b(f1.x); a[5]=f2b(f1.y); a[6]=f2b(f1.z); a[7]=f2b(f1.w);
            a0[kt] = a;
            asm volatile("" : "+a"(a0[kt]));
            f0 = *(const float4*)(xr1 + kt * 32);
            f1 = *(const float4*)(xr1 + kt * 32 + 4);
            a[0]=f2b(f0.x); a[1]=f2b(f0.y); a[2]=f2b(f0.z); a[3]=f2b(f0.w);
            a[4]=f2b(f1.x); a[5]=f2b(f1.y); a[6]=f2b(f1.z); a[7]=f2b(f1.w);
            a1[kt] = a;
            asm volatile("" : "+a"(a1[kt]));
        }
    }

    // ---- Staging map: tile chunk = 16 Qrows x 512 k = 2048 float4 / 512 thr
    int s_nn[4], s_k4[4];
    #pragma unroll
    for (int i = 0; i < 4; ++i) {
        const int idx = tid + i * 512;
        s_nn[i] = idx >> 7;        // 0..15
        s_k4[i] = idx & 127;       // float4 within KH
    }

    // prefetch tile 0
    float4 pf[4];
    #pragma unroll
    for (int i = 0; i < 4; ++i)
        pf[i] = *(const float4*)(Q + (size_t)(tbase * 16 + s_nn[i]) * DD + kofs + s_k4[i] * 4);

    float acc0[4] = {0,0,0,0}, acc1[4] = {0,0,0,0};

    const short* bp0 = &lq[0][l15 * LDS_ROW + quad * 8];
    const short* bp1 = &lq[1][l15 * LDS_ROW + quad * 8];

    for (int t = 0; t < NT; ++t) {
        const int tg = tbase + t;

        // store staged tile (fp32 -> bf16) into buf t&1
        short* dst = &lq[t & 1][0];
        #pragma unroll
        for (int i = 0; i < 4; ++i) {
            const float4 f = pf[i];
            short4 s;
            s.x=f2b(f.x); s.y=f2b(f.y); s.z=f2b(f.z); s.w=f2b(f.w);
            *(short4*)&dst[s_nn[i] * LDS_ROW + s_k4[i] * 4] = s;
        }
        __syncthreads();

        // issue next tile's prefetch AFTER the barrier: in flight across MFMA
        if (t + 1 < NT) {
            #pragma unroll
            for (int i = 0; i < 4; ++i)
                pf[i] = *(const float4*)(Q + (size_t)((tg + 1) * 16 + s_nn[i]) * DD + kofs + s_k4[i] * 4);
        }

        // fused-dot operands for this tile (consumed after 16 MFMA steps)
        const int n = tg * 16 + l15;
        const float bn = (khalf == 0) ? bvec[n] : 0.f;
        float xv0[4], xv1[4];
        {
            const float* xc = x + (size_t)(row_base + quad * 4) * DD + n;
            #pragma unroll
            for (int r = 0; r < 4; ++r) {
                xv0[r] = xc[(size_t)r * DD];
                xv1[r] = xc[(size_t)(r + 16) * DD];
            }
        }

        // MFMA: each B-frag feeds both A-groups
        v4f cf0 = {0,0,0,0}, cf1 = {0,0,0,0};
        const short* bp = (t & 1) ? bp1 : bp0;
        #pragma unroll
        for (int s = 0; s < KSTEP; ++s) {
            const v8s bfrag = *(const v8s*)(bp + s * 32);
            cf0 = __builtin_amdgcn_mfma_f32_16x16x32_bf16(a0[s], bfrag, cf0, 0, 0, 0);
            cf1 = __builtin_amdgcn_mfma_f32_16x16x32_bf16(a1[s], bfrag, cf1, 0, 0, 0);
        }

        // fused dot: C layout col = lane&15, row = quad*4 + reg
        #pragma unroll
        for (int r = 0; r < 4; ++r) {
            acc0[r] += (cf0[r] + bn) * xv0[r];
            acc1[r] += (cf1[r] + bn) * xv1[r];
        }
    }

    // ---- reduce across the 16 lanes of each quad, atomic into y ----
    const float cc = (seg == 0) ? cptr[0] : 0.f;  // c added once per row
    #pragma unroll
    for (int r = 0; r < 4; ++r) {
        float v = acc0[r];
        v += __shfl_xor(v, 1); v += __shfl_xor(v, 2);
        v += __shfl_xor(v, 4); v += __shfl_xor(v, 8);
        if (l15 == 0) atomicAdd(&y[row_base + quad * 4 + r], v + cc);

        float w = acc1[r];
        w += __shfl_xor(w, 1); w += __shfl_xor(w, 2);
        w += __shfl_xor(w, 4); w += __shfl_xor(w, 8);
        if (l15 == 0) atomicAdd(&y[row_base + 16 + quad * 4 + r], w + cc);
    }
}

extern "C" void kernel_launch(void* const* d_in, const int* in_sizes, int n_in,
                              void* d_out, int out_size, void* d_ws, size_t ws_size,
                              hipStream_t stream)
{
    const float* x = (const float*)d_in[0];
    const float* Q = (const float*)d_in[1];
    const float* b = (const float*)d_in[2];
    const float* c = (const float*)d_in[3];
    float* y = (float*)d_out;

    hipMemsetAsync(y, 0, (size_t)out_size * sizeof(float), stream);
    quad_kernel<<<dim3(512), dim3(512), 0, stream>>>(x, Q, b, c, y);
}

// Round 4
// 156.298 us; speedup vs baseline: 2.1257x; 2.1257x over previous
//
#include <hip/hip_runtime.h>
#include <hip/hip_bf16.h>

// y_i = x_i^T Q x_i + b^T x_i + c ; N=16384, D=1024, fp32.
// Round 4: R=64 rows/wave (4 x 16-row A-groups share each LDS B-frag ->
// LDS B-traffic = MFMA_time/1.4, 4 independent MFMA chains), KH=256
// (K-split 4) keeps A at 128 AGPRs. CRITICAL: __launch_bounds__(512,2) ->
// 256-reg unified budget (128 AGPR + ~100 VGPR fits). Round 3's (512,4)
// capped the budget at 128 and spilled A to scratch (WRITE_SIZE 76.8 MB,
// 855 MB fetch, 250us). Col-split 2 -> grid 256. One barrier per tile,
// prefetch issued after the barrier. atomicAdd partial y (memset first).

#define DD 1024
#define KH 256           // K per block (K-split 4)
#define KSTEP 8          // KH/32 MFMA k-steps per tile
#define NTT 32           // column tiles per col-half (512 n / 16)
#define LDS_ROW 264      // shorts: 256 + 8 pad

typedef short v8s __attribute__((ext_vector_type(8)));
typedef float v4f __attribute__((ext_vector_type(4)));

__device__ __forceinline__ short f2b(float f) {
    union { __hip_bfloat16 h; short s; } u;
    u.h = __float2bfloat16(f);
    return u.s;
}

__global__ __launch_bounds__(512, 2)
void quad_kernel(const float* __restrict__ x, const float* __restrict__ Q,
                 const float* __restrict__ bvec, const float* __restrict__ cptr,
                 float* __restrict__ y)
{
    __shared__ short lq[2][16 * LDS_ROW];   // 2 x 8.25 KB staging buffers

    const int tid  = threadIdx.x;
    const int lane = tid & 63;
    const int wave = tid >> 6;
    const int quad = lane >> 4;
    const int l15  = lane & 15;

    const int seg  = blockIdx.x & 7;     // kq*2 + cs
    const int rblk = blockIdx.x >> 3;    // 0..31
    const int kq   = seg >> 1;           // K quarter 0..3
    const int cs   = seg & 1;            // column half 0..1

    const int row_base = rblk * 512 + wave * 64;   // 64 rows per wave
    const int kofs  = kq * KH;
    const int tbase = cs * NTT;

    // ---- Phase 1: A = x[64 rows][kofs..kofs+256) bf16 frags in AGPRs ----
    // A layout (16x16x32): m = lane&15, k = quad*8 + j (8 contiguous bf16)
    v8s a[4][KSTEP];
    #pragma unroll
    for (int g = 0; g < 4; ++g) {
        const float* xr = x + (size_t)(row_base + g * 16 + l15) * DD + kofs + quad * 8;
        #pragma unroll
        for (int s = 0; s < KSTEP; ++s) {
            const float4 f0 = *(const float4*)(xr + s * 32);
            const float4 f1 = *(const float4*)(xr + s * 32 + 4);
            v8s t;
            t[0]=f2b(f0.x); t[1]=f2b(f0.y); t[2]=f2b(f0.z); t[3]=f2b(f0.w);
            t[4]=f2b(f1.x); t[5]=f2b(f1.y); t[6]=f2b(f1.z); t[7]=f2b(f1.w);
            a[g][s] = t;
            asm volatile("" : "+a"(a[g][s]));   // force AGPR residency
        }
    }

    // ---- Staging map: tile = 16 Qrows x 256 floats = 1024 float4 / 512 thr
    int s_nn[2], s_k4[2];
    #pragma unroll
    for (int i = 0; i < 2; ++i) {
        const int idx = tid + i * 512;
        s_nn[i] = idx >> 6;        // 0..15
        s_k4[i] = idx & 63;        // float4 within KH
    }

    // prefetch tile 0
    float4 pf[2];
    #pragma unroll
    for (int i = 0; i < 2; ++i)
        pf[i] = *(const float4*)(Q + (size_t)(tbase * 16 + s_nn[i]) * DD + kofs + s_k4[i] * 4);

    float acc[4][4];
    #pragma unroll
    for (int g = 0; g < 4; ++g)
        #pragma unroll
        for (int r = 0; r < 4; ++r) acc[g][r] = 0.f;

    for (int t = 0; t < NTT; ++t) {
        const int tg = tbase + t;

        // store staged tile (fp32 -> bf16) into buf t&1
        short* dst = &lq[t & 1][0];
        #pragma unroll
        for (int i = 0; i < 2; ++i) {
            const float4 f = pf[i];
            short4 s;
            s.x=f2b(f.x); s.y=f2b(f.y); s.z=f2b(f.z); s.w=f2b(f.w);
            *(short4*)&dst[s_nn[i] * LDS_ROW + s_k4[i] * 4] = s;
        }
        __syncthreads();

        // next tile's prefetch AFTER the barrier: in flight across MFMA
        if (t + 1 < NTT) {
            #pragma unroll
            for (int i = 0; i < 2; ++i)
                pf[i] = *(const float4*)(Q + (size_t)((tg + 1) * 16 + s_nn[i]) * DD + kofs + s_k4[i] * 4);
        }

        // fused-dot operands for this tile (consumed after the MFMAs)
        const int n = tg * 16 + l15;
        const float bn = (kq == 0) ? bvec[n] : 0.f;
        float xv[4][4];
        {
            const float* xc = x + (size_t)(row_base + quad * 4) * DD + n;
            #pragma unroll
            for (int g = 0; g < 4; ++g)
                #pragma unroll
                for (int r = 0; r < 4; ++r)
                    xv[g][r] = xc[(size_t)(g * 16 + r) * DD];
        }

        // MFMA: each B-frag feeds all 4 A-groups (4 independent chains)
        v4f cf[4];
        #pragma unroll
        for (int g = 0; g < 4; ++g) cf[g] = (v4f){0.f, 0.f, 0.f, 0.f};
        const short* bp = &lq[t & 1][l15 * LDS_ROW + quad * 8];
        #pragma unroll
        for (int s = 0; s < KSTEP; ++s) {
            const v8s bfrag = *(const v8s*)(bp + s * 32);
            #pragma unroll
            for (int g = 0; g < 4; ++g)
                cf[g] = __builtin_amdgcn_mfma_f32_16x16x32_bf16(a[g][s], bfrag, cf[g], 0, 0, 0);
        }

        // fused dot: C layout col = lane&15, row = quad*4 + reg
        #pragma unroll
        for (int g = 0; g < 4; ++g)
            #pragma unroll
            for (int r = 0; r < 4; ++r)
                acc[g][r] += (cf[g][r] + bn) * xv[g][r];
    }

    // ---- reduce across the 16 lanes of each quad, atomic into y ----
    const float cc = (seg == 0) ? cptr[0] : 0.f;  // c added once per row
    #pragma unroll
    for (int g = 0; g < 4; ++g) {
        #pragma unroll
        for (int r = 0; r < 4; ++r) {
            float v = acc[g][r];
            v += __shfl_xor(v, 1); v += __shfl_xor(v, 2);
            v += __shfl_xor(v, 4); v += __shfl_xor(v, 8);
            if (l15 == 0)
                atomicAdd(&y[row_base + g * 16 + quad * 4 + r], v + cc);
        }
    }
}

extern "C" void kernel_launch(void* const* d_in, const int* in_sizes, int n_in,
                              void* d_out, int out_size, void* d_ws, size_t ws_size,
                              hipStream_t stream)
{
    const float* x = (const float*)d_in[0];
    const float* Q = (const float*)d_in[1];
    const float* b = (const float*)d_in[2];
    const float* c = (const float*)d_in[3];
    float* y = (float*)d_out;

    hipMemsetAsync(y, 0, (size_t)out_size * sizeof(float), stream);
    quad_kernel<<<dim3(256), dim3(512), 0, stream>>>(x, Q, b, c, y);
}